// Round 1
// baseline (440.975 us; speedup 1.0000x reference)
//
#include <hip/hip_runtime.h>

typedef unsigned short u16;
typedef unsigned int   u32;
typedef short v8s __attribute__((ext_vector_type(8)));   // 8 bf16 (A/B frag, 4 VGPR)
typedef float v4f __attribute__((ext_vector_type(4)));   // 4 fp32 (C/D frag)

#define DEV __device__ __forceinline__
#define MFMA(a,b,c) __builtin_amdgcn_mfma_f32_16x16x32_bf16((a),(b),(c),0,0,0)

constexpr int Bb = 32, Tt = 64, Ff = 128, Dd = 64, Hh = 4, Kk = 32;

DEV u16 f2b(float f) {                       // RNE (prep kernel only)
    u32 u = __float_as_uint(f);
    return (u16)((u + 0x7fffu + ((u >> 16) & 1u)) >> 16);
}
// HW packed f32->bf16 (RNE), 1 VALU op for 2 values (learn_hip T12 recipe)
DEV u32 pk2(float a, float b) {
    u32 r;
    asm("v_cvt_pk_bf16_f32 %0, %1, %2" : "=v"(r) : "v"(a), "v"(b));
    return r;
}

// ---- prep: convert all weights to bf16 containers in ws (128 KB) ----
// ws layout (u16):
//   [0, 49152)      : 6 proj  x [h][ch=32][d=64]   (tq,tk,tv,fq,fk,fv)
//   [49152, 65536)  : 2 woT   x [h][d=64][k=32]    (to, fo)
__global__ __launch_bounds__(256)
void prep_weights(const float* __restrict__ tq, const float* __restrict__ tk,
                  const float* __restrict__ tv, const float* __restrict__ fq,
                  const float* __restrict__ fk, const float* __restrict__ fv,
                  const float* __restrict__ to_, const float* __restrict__ fo,
                  u16* __restrict__ ws)
{
    int idx = blockIdx.x * 256 + threadIdx.x;          // 0..65535
    if (idx < 49152) {
        int p = idx >> 13, rem = idx & 8191;           // [h][ch][d]
        int h = rem >> 11, ch = (rem >> 6) & 31, d = rem & 63;
        const float* w = (p==0)?tq:(p==1)?tk:(p==2)?tv:(p==3)?fq:(p==4)?fk:fv;
        ws[idx] = f2b(w[d*128 + h*32 + ch]);           // w[d][h][ch]
    } else {
        int i2 = idx - 49152;
        int path = i2 >> 13, rem = i2 & 8191;          // [h][d][k]
        int h = rem >> 11, d = (rem >> 5) & 63, k2 = rem & 31;
        const float* w = path ? fo : to_;
        ws[idx] = f2b(w[h*2048 + k2*64 + d]);          // wo[h][k][d]
    }
}

// Fragment facts (HW-verified, learn_hip m89/m120):
//   A-frag: lane = A[m][k], m=lane&15, k=quad*8+j  (container row-major [m][k])
//   B-frag: lane = B[k][n], n=lane&15, k=quad*8+j  (container [n][k])
//   C/D:    lane = D[row][col], col=lane&15, row=quad*4+r
//   MFMA(A,B) -> D[m][n] = sum_k A[m][k]*B[n][k]; swapping operands transposes D.
// MODE 0: temporal (NR=64 rows=T, block per (b,f)), writes fp32 partial.
// MODE 1: feature (NR=128 rows=F, block per (b,t)), read-add-write final.
//
// P is WAVE-LOCAL (each wave writes/reads only its own 16 q-rows, no barrier):
// stage it through a quarter-size [NR][40] buffer (32 krows + pad) consumed
// per-ks.  In-order per-wave DS execution guarantees write->read->overwrite
// ordering without any sync.  LDS: feature 39424 B (4 blk/CU, 32 waves),
// temporal 19968 B (8 blk/CU, 32 waves).  launch_bounds(…,8) pins 8 waves/SIMD.
template<int NR, int MODE>
__global__ __launch_bounds__(NR*4, 8)
void axial_mfma(const float* __restrict__ x, const u16* __restrict__ wsw,
                const float* __restrict__ bq, const float* __restrict__ bk,
                const float* __restrict__ bv, const float* __restrict__ bo,
                float* __restrict__ out)
{
    constexpr int W   = NR / 16;      // waves per block
    constexpr int QP  = 40;           // Q/K/O row pitch (80B: 16B-aligned, 2-way-free banks)
    constexpr int NRp = NR + 8;       // V^T pitch (16B-aligned)
    constexpr int PP  = 40;           // P quarter-buffer pitch: 32 krows + 8 pad
    constexpr int o_q  = 0;                   // Q, reused as O  [NR][QP]   (own-wave rows only)
    constexpr int o_k  = o_q + NR * QP;       // K    [NR][QP]
    constexpr int o_vt = o_k + NR * QP;       // V^T  [32][NRp]
    constexpr int o_p  = o_vt + 32 * NRp;     // P staging [NR][PP] (own-wave rows only)
    constexpr int SMEM = o_p + NR * PP;       // feature: 39424 B, temporal: 19968 B
    __shared__ alignas(16) u16 sm[SMEM];

    const int tid  = threadIdx.x;
    const int w    = tid >> 6;
    const int lane = tid & 63;
    const int quad = lane >> 4;
    const int l15  = lane & 15;
    const int bid  = blockIdx.x;

    int base, rstride;
    if (MODE == 0) { int b = bid >> 7, f = bid & 127; base = b*(Tt*Ff*Dd) + f*Dd; rstride = Ff*Dd; }
    else           { base = bid * (Ff*Dd); rstride = Dd; }

    constexpr int PB = (MODE == 0) ? 0 : 3;
    const u16* wql = wsw + (PB+0)*8192;
    const u16* wkl = wsw + (PB+1)*8192;
    const u16* wvl = wsw + (PB+2)*8192;
    const u16* wol = wsw + 49152 + MODE*8192;

    // ---- X fragments (dual-use as A or B; same lane mapping), row w*16+l15 ----
    v8s xfrag[2];
#pragma unroll
    for (int ks = 0; ks < 2; ++ks) {
        const float* xp = x + base + (w*16 + l15)*rstride + ks*32 + quad*8;
        float4 a = *reinterpret_cast<const float4*>(xp);
        float4 b = *reinterpret_cast<const float4*>(xp + 4);
        v8s f;
        u32* fu = reinterpret_cast<u32*>(&f);
        fu[0] = pk2(a.x, a.y); fu[1] = pk2(a.z, a.w);
        fu[2] = pk2(b.x, b.y); fu[3] = pk2(b.z, b.w);
        xfrag[ks] = f;
    }

    v4f outAcc[4];
#pragma unroll
    for (int i = 0; i < 4; ++i) outAcc[i] = (v4f){0.f,0.f,0.f,0.f};

    const float scale = 0.17677669529663687f;   // 1/sqrt(32)
    const v4f vzero = (v4f){0.f,0.f,0.f,0.f};
    const int qrow_base = o_q + (w*16+l15)*QP;
    const int prow_base = o_p + (w*16+l15)*PP;

#pragma unroll 1
    for (int h = 0; h < Hh; ++h) {
        // barrier 1: prev head's cross-wave K/V^T reads complete before overwrite
        __syncthreads();

        // ===== Q^T proj: MFMA(Wq^T, X) -> D[ch][qrow]; lane = 4 consecutive ch =====
        {
            const u16* wb = wql + h*2048;
#pragma unroll
            for (int nt = 0; nt < 2; ++nt) {
                v4f acc = vzero;
#pragma unroll
                for (int ks = 0; ks < 2; ++ks) {
                    v8s wf = *reinterpret_cast<const v8s*>(wb + (nt*16+l15)*64 + ks*32 + quad*8);
                    acc = MFMA(wf, xfrag[ks], acc);
                }
                float4 b4 = *reinterpret_cast<const float4*>(bq + h*32 + nt*16 + quad*4);
                u32 lo = pk2((acc[0]+b4.x)*scale, (acc[1]+b4.y)*scale);
                u32 hi = pk2((acc[2]+b4.z)*scale, (acc[3]+b4.w)*scale);
                *reinterpret_cast<uint2*>(&sm[qrow_base + nt*16 + quad*4]) = make_uint2(lo, hi);
            }
        }
        // ===== K^T proj =====
        {
            const u16* wb = wkl + h*2048;
#pragma unroll
            for (int nt = 0; nt < 2; ++nt) {
                v4f acc = vzero;
#pragma unroll
                for (int ks = 0; ks < 2; ++ks) {
                    v8s wf = *reinterpret_cast<const v8s*>(wb + (nt*16+l15)*64 + ks*32 + quad*8);
                    acc = MFMA(wf, xfrag[ks], acc);
                }
                float4 b4 = *reinterpret_cast<const float4*>(bk + h*32 + nt*16 + quad*4);
                u32 lo = pk2(acc[0]+b4.x, acc[1]+b4.y);
                u32 hi = pk2(acc[2]+b4.z, acc[3]+b4.w);
                *reinterpret_cast<uint2*>(&sm[o_k + (w*16+l15)*QP + nt*16 + quad*4]) = make_uint2(lo, hi);
            }
        }
        // ===== V proj (non-transposed): D[krow][ch], lane = 4 consecutive krows =====
        {
            const u16* wb = wvl + h*2048;
#pragma unroll
            for (int nt = 0; nt < 2; ++nt) {
                v4f acc = vzero;
#pragma unroll
                for (int ks = 0; ks < 2; ++ks) {
                    v8s wf = *reinterpret_cast<const v8s*>(wb + (nt*16+l15)*64 + ks*32 + quad*8);
                    acc = MFMA(xfrag[ks], wf, acc);
                }
                float bias = bv[h*32 + nt*16 + l15];
                u32 lo = pk2(acc[0]+bias, acc[1]+bias);
                u32 hi = pk2(acc[2]+bias, acc[3]+bias);
                int ch = nt*16 + l15;
                *reinterpret_cast<uint2*>(&sm[o_vt + ch*NRp + w*16 + quad*4]) = make_uint2(lo, hi);
            }
        }
        // barrier 2: K, V^T (cross-wave operands) visible
        __syncthreads();

        // ===== S^T = MFMA(K, Q) -> D[krow][qrow]; lane: qrow=l15, 4 consec krows =====
        v8s qf = *reinterpret_cast<const v8s*>(&sm[qrow_base + quad*8]);   // own-wave
        v4f S[W];
#pragma unroll
        for (int ct = 0; ct < W; ++ct) {
            v8s kf = *reinterpret_cast<const v8s*>(&sm[o_k + (ct*16+l15)*QP + quad*8]);
            S[ct] = MFMA(kf, qf, vzero);
        }
        // ===== softmax over keys (per-lane row; tree reduce then xor 16,32) =====
        float cm[W];
#pragma unroll
        for (int ct = 0; ct < W; ++ct)
            cm[ct] = fmaxf(fmaxf(S[ct][0], S[ct][1]), fmaxf(S[ct][2], S[ct][3]));
        float mm = cm[0];
#pragma unroll
        for (int ct = 1; ct < W; ++ct) mm = fmaxf(mm, cm[ct]);
        mm = fmaxf(mm, __shfl_xor(mm, 16));
        mm = fmaxf(mm, __shfl_xor(mm, 32));
        float ss = 0.f;
#pragma unroll
        for (int ct = 0; ct < W; ++ct)
#pragma unroll
            for (int r = 0; r < 4; ++r) { float p = __expf(S[ct][r] - mm); S[ct][r] = p; ss += p; }
        ss += __shfl_xor(ss, 16);
        ss += __shfl_xor(ss, 32);
        float rl = 1.f / ss;       // deferred: applied to O, not to P (softmax linear in P)

        // pack unnormalized P early so S[] dies (keeps VGPR under the 64 cap)
        u32 pkv[2*W];
#pragma unroll
        for (int ct = 0; ct < W; ++ct) {
            pkv[2*ct+0] = pk2(S[ct][0], S[ct][1]);
            pkv[2*ct+1] = pk2(S[ct][2], S[ct][3]);
        }

        // ===== O^T = MFMA(V^T, P) via quarter P staging buffer (wave-local) =====
        v4f Oacc[2] = { vzero, vzero };
#pragma unroll
        for (int ks = 0; ks < NR/32; ++ks) {
            // stage krows [ks*32, ks*32+32) of this wave's 16 q-rows
            *reinterpret_cast<uint2*>(&sm[prow_base +      quad*4]) = make_uint2(pkv[4*ks+0], pkv[4*ks+1]);
            *reinterpret_cast<uint2*>(&sm[prow_base + 16 + quad*4]) = make_uint2(pkv[4*ks+2], pkv[4*ks+3]);
            v8s pf = *reinterpret_cast<const v8s*>(&sm[prow_base + quad*8]);  // own-wave, in-order DS
#pragma unroll
            for (int nt = 0; nt < 2; ++nt) {
                v8s vf = *reinterpret_cast<const v8s*>(&sm[o_vt + (nt*16+l15)*NRp + ks*32 + quad*8]);
                Oacc[nt] = MFMA(vf, pf, Oacc[nt]);
            }
        }
        // O into Q container (own-wave row; qf already consumed), rl folded here
#pragma unroll
        for (int nt = 0; nt < 2; ++nt) {
            u32 lo = pk2(Oacc[nt][0]*rl, Oacc[nt][1]*rl);
            u32 hi = pk2(Oacc[nt][2]*rl, Oacc[nt][3]*rl);
            *reinterpret_cast<uint2*>(&sm[qrow_base + nt*16 + quad*4]) = make_uint2(lo, hi);
        }

        // ===== out^T += MFMA(Wo^T, O) -> D[d][qrow]; lane = 4 consec d =====
        v8s of = *reinterpret_cast<const v8s*>(&sm[qrow_base + quad*8]);   // own-wave
        {
            const u16* wb = wol + h*2048;
#pragma unroll
            for (int nt = 0; nt < 4; ++nt) {
                v8s wf = *reinterpret_cast<const v8s*>(wb + (nt*16+l15)*32 + quad*8);
                outAcc[nt] = MFMA(wf, of, outAcc[nt]);
            }
        }
    }

    // ===== epilogue: lane owns row w*16+l15, d = nt*16+quad*4 .. +3 (float4) =====
    float* orow = out + base + (w*16 + l15)*rstride;
#pragma unroll
    for (int nt = 0; nt < 4; ++nt) {
        int d0 = nt*16 + quad*4;
        float4 b4 = *reinterpret_cast<const float4*>(bo + d0);
        float4 v = make_float4(outAcc[nt][0]+b4.x, outAcc[nt][1]+b4.y,
                               outAcc[nt][2]+b4.z, outAcc[nt][3]+b4.w);
        if (MODE == 1) {
            float4 p = *reinterpret_cast<const float4*>(orow + d0);
            v.x += p.x; v.y += p.y; v.z += p.z; v.w += p.w;
        }
        *reinterpret_cast<float4*>(orow + d0) = v;
    }
}

extern "C" void kernel_launch(void* const* d_in, const int* in_sizes, int n_in,
                              void* d_out, int out_size, void* d_ws, size_t ws_size,
                              hipStream_t stream) {
    const float* x   = (const float*)d_in[0];
    const float* tqw = (const float*)d_in[1];  const float* tqb = (const float*)d_in[2];
    const float* tkw = (const float*)d_in[3];  const float* tkb = (const float*)d_in[4];
    const float* tvw = (const float*)d_in[5];  const float* tvb = (const float*)d_in[6];
    const float* fqw = (const float*)d_in[7];  const float* fqb = (const float*)d_in[8];
    const float* fkw = (const float*)d_in[9];  const float* fkb = (const float*)d_in[10];
    const float* fvw = (const float*)d_in[11]; const float* fvb = (const float*)d_in[12];
    const float* tow = (const float*)d_in[13]; const float* tob = (const float*)d_in[14];
    const float* fow = (const float*)d_in[15]; const float* fob = (const float*)d_in[16];
    float* out = (float*)d_out;
    u16* ws = (u16*)d_ws;   // 128 KB

    hipLaunchKernelGGL(prep_weights, dim3(256), dim3(256), 0, stream,
                       tqw, tkw, tvw, fqw, fkw, fvw, tow, fow, ws);
    hipLaunchKernelGGL((axial_mfma<64,0>), dim3(Bb*Ff), dim3(256), 0, stream,
                       x, ws, tqb, tkb, tvb, tob, out);
    hipLaunchKernelGGL((axial_mfma<128,1>), dim3(Bb*Tt), dim3(512), 0, stream,
                       x, ws, fqb, fkb, fvb, fob, out);
}

// Round 2
// 394.244 us; speedup vs baseline: 1.1185x; 1.1185x over previous
//
#include <hip/hip_runtime.h>

typedef unsigned short u16;
typedef unsigned int   u32;
typedef short v8s __attribute__((ext_vector_type(8)));   // 8 bf16 (A/B frag, 4 VGPR)
typedef float v4f __attribute__((ext_vector_type(4)));   // 4 fp32 (C/D frag)

#define DEV __device__ __forceinline__
#define MFMA(a,b,c) __builtin_amdgcn_mfma_f32_16x16x32_bf16((a),(b),(c),0,0,0)

constexpr int Bb = 32, Tt = 64, Ff = 128, Dd = 64, Hh = 4, Kk = 32;

DEV u16 f2b(float f) {                       // RNE (prep kernel only)
    u32 u = __float_as_uint(f);
    return (u16)((u + 0x7fffu + ((u >> 16) & 1u)) >> 16);
}
// HW packed f32->bf16 (RNE), 1 VALU op for 2 values (learn_hip T12 recipe)
DEV u32 pk2(float a, float b) {
    u32 r;
    asm("v_cvt_pk_bf16_f32 %0, %1, %2" : "=v"(r) : "v"(a), "v"(b));
    return r;
}

// ---- prep: convert all weights to bf16 containers in ws (128 KB) ----
// ws layout (u16):
//   [0, 49152)      : 6 proj  x [h][ch=32][d=64]   (tq,tk,tv,fq,fk,fv)
//   [49152, 65536)  : 2 woT   x [h][d=64][k=32]    (to, fo)
__global__ __launch_bounds__(256)
void prep_weights(const float* __restrict__ tq, const float* __restrict__ tk,
                  const float* __restrict__ tv, const float* __restrict__ fq,
                  const float* __restrict__ fk, const float* __restrict__ fv,
                  const float* __restrict__ to_, const float* __restrict__ fo,
                  u16* __restrict__ ws)
{
    int idx = blockIdx.x * 256 + threadIdx.x;          // 0..65535
    if (idx < 49152) {
        int p = idx >> 13, rem = idx & 8191;           // [h][ch][d]
        int h = rem >> 11, ch = (rem >> 6) & 31, d = rem & 63;
        const float* w = (p==0)?tq:(p==1)?tk:(p==2)?tv:(p==3)?fq:(p==4)?fk:fv;
        ws[idx] = f2b(w[d*128 + h*32 + ch]);           // w[d][h][ch]
    } else {
        int i2 = idx - 49152;
        int path = i2 >> 13, rem = i2 & 8191;          // [h][d][k]
        int h = rem >> 11, d = (rem >> 5) & 63, k2 = rem & 31;
        const float* w = path ? fo : to_;
        ws[idx] = f2b(w[h*2048 + k2*64 + d]);          // wo[h][k][d]
    }
}

// Fragment facts (HW-verified, learn_hip m89/m120):
//   A-frag: lane = A[m][k], m=lane&15, k=quad*8+j  (container row-major [m][k])
//   B-frag: lane = B[k][n], n=lane&15, k=quad*8+j  (container [n][k])
//   C/D:    lane = D[row][col], col=lane&15, row=quad*4+r
//   MFMA(A,B) -> D[m][n] = sum_k A[m][k]*B[n][k]; swapping operands transposes D.
// MODE 0: temporal (NR=64 rows=T, block per (b,f)), writes fp32 partial.
// MODE 1: feature (NR=128 rows=F, block per (b,t)), read-add-write final.
//
// P is WAVE-LOCAL (each wave writes/reads only its own 16 q-rows, no barrier):
// staged through a quarter-size [NR][40] buffer (32 krows + pad), packed
// directly from S[] per-ks.  In-order per-wave DS execution guarantees
// write->read->overwrite ordering without sync.  LDS: feature 39424 B
// (4 blk/CU possible), temporal 19968 B (8 blk/CU possible).
// NO min-waves launch_bounds arg: round-1 showed (512,8) forces the unified
// VGPR+AGPR budget to 64/wave -> massive scratch spills (WRITE_SIZE 315 MB vs
// 64 MB ideal).  Round-0 allocation (56 VGPR) already permits 8 waves/SIMD.
template<int NR, int MODE>
__global__ __launch_bounds__(NR*4)
void axial_mfma(const float* __restrict__ x, const u16* __restrict__ wsw,
                const float* __restrict__ bq, const float* __restrict__ bk,
                const float* __restrict__ bv, const float* __restrict__ bo,
                float* __restrict__ out)
{
    constexpr int W   = NR / 16;      // waves per block
    constexpr int QP  = 40;           // Q/K/O row pitch (80B: 16B-aligned, 2-way-free banks)
    constexpr int NRp = NR + 8;       // V^T pitch (16B-aligned)
    constexpr int PP  = 40;           // P quarter-buffer pitch: 32 krows + 8 pad
    constexpr int o_q  = 0;                   // Q, reused as O  [NR][QP]   (own-wave rows only)
    constexpr int o_k  = o_q + NR * QP;       // K    [NR][QP]
    constexpr int o_vt = o_k + NR * QP;       // V^T  [32][NRp]
    constexpr int o_p  = o_vt + 32 * NRp;     // P staging [NR][PP] (own-wave rows only)
    constexpr int SMEM = o_p + NR * PP;       // feature: 39424 B, temporal: 19968 B
    __shared__ alignas(16) u16 sm[SMEM];

    const int tid  = threadIdx.x;
    const int w    = tid >> 6;
    const int lane = tid & 63;
    const int quad = lane >> 4;
    const int l15  = lane & 15;
    const int bid  = blockIdx.x;

    int base, rstride;
    if (MODE == 0) { int b = bid >> 7, f = bid & 127; base = b*(Tt*Ff*Dd) + f*Dd; rstride = Ff*Dd; }
    else           { base = bid * (Ff*Dd); rstride = Dd; }

    constexpr int PB = (MODE == 0) ? 0 : 3;
    const u16* wql = wsw + (PB+0)*8192;
    const u16* wkl = wsw + (PB+1)*8192;
    const u16* wvl = wsw + (PB+2)*8192;
    const u16* wol = wsw + 49152 + MODE*8192;

    // ---- X fragments (dual-use as A or B; same lane mapping), row w*16+l15 ----
    v8s xfrag[2];
#pragma unroll
    for (int ks = 0; ks < 2; ++ks) {
        const float* xp = x + base + (w*16 + l15)*rstride + ks*32 + quad*8;
        float4 a = *reinterpret_cast<const float4*>(xp);
        float4 b = *reinterpret_cast<const float4*>(xp + 4);
        v8s f;
        u32* fu = reinterpret_cast<u32*>(&f);
        fu[0] = pk2(a.x, a.y); fu[1] = pk2(a.z, a.w);
        fu[2] = pk2(b.x, b.y); fu[3] = pk2(b.z, b.w);
        xfrag[ks] = f;
    }

    v4f outAcc[4];
#pragma unroll
    for (int i = 0; i < 4; ++i) outAcc[i] = (v4f){0.f,0.f,0.f,0.f};

    const float scale = 0.17677669529663687f;   // 1/sqrt(32)
    const v4f vzero = (v4f){0.f,0.f,0.f,0.f};
    const int qrow_base = o_q + (w*16+l15)*QP;
    const int prow_base = o_p + (w*16+l15)*PP;

#pragma unroll 1
    for (int h = 0; h < Hh; ++h) {
        // barrier 1: prev head's cross-wave K/V^T reads complete before overwrite
        __syncthreads();

        // ===== Q^T proj: MFMA(Wq^T, X) -> D[ch][qrow]; lane = 4 consecutive ch =====
        {
            const u16* wb = wql + h*2048;
#pragma unroll
            for (int nt = 0; nt < 2; ++nt) {
                v4f acc = vzero;
#pragma unroll
                for (int ks = 0; ks < 2; ++ks) {
                    v8s wf = *reinterpret_cast<const v8s*>(wb + (nt*16+l15)*64 + ks*32 + quad*8);
                    acc = MFMA(wf, xfrag[ks], acc);
                }
                float4 b4 = *reinterpret_cast<const float4*>(bq + h*32 + nt*16 + quad*4);
                u32 lo = pk2((acc[0]+b4.x)*scale, (acc[1]+b4.y)*scale);
                u32 hi = pk2((acc[2]+b4.z)*scale, (acc[3]+b4.w)*scale);
                *reinterpret_cast<uint2*>(&sm[qrow_base + nt*16 + quad*4]) = make_uint2(lo, hi);
            }
        }
        // ===== K^T proj =====
        {
            const u16* wb = wkl + h*2048;
#pragma unroll
            for (int nt = 0; nt < 2; ++nt) {
                v4f acc = vzero;
#pragma unroll
                for (int ks = 0; ks < 2; ++ks) {
                    v8s wf = *reinterpret_cast<const v8s*>(wb + (nt*16+l15)*64 + ks*32 + quad*8);
                    acc = MFMA(wf, xfrag[ks], acc);
                }
                float4 b4 = *reinterpret_cast<const float4*>(bk + h*32 + nt*16 + quad*4);
                u32 lo = pk2(acc[0]+b4.x, acc[1]+b4.y);
                u32 hi = pk2(acc[2]+b4.z, acc[3]+b4.w);
                *reinterpret_cast<uint2*>(&sm[o_k + (w*16+l15)*QP + nt*16 + quad*4]) = make_uint2(lo, hi);
            }
        }
        // ===== V proj (non-transposed): D[krow][ch], lane = 4 consecutive krows =====
        {
            const u16* wb = wvl + h*2048;
#pragma unroll
            for (int nt = 0; nt < 2; ++nt) {
                v4f acc = vzero;
#pragma unroll
                for (int ks = 0; ks < 2; ++ks) {
                    v8s wf = *reinterpret_cast<const v8s*>(wb + (nt*16+l15)*64 + ks*32 + quad*8);
                    acc = MFMA(xfrag[ks], wf, acc);
                }
                float bias = bv[h*32 + nt*16 + l15];
                u32 lo = pk2(acc[0]+bias, acc[1]+bias);
                u32 hi = pk2(acc[2]+bias, acc[3]+bias);
                int ch = nt*16 + l15;
                *reinterpret_cast<uint2*>(&sm[o_vt + ch*NRp + w*16 + quad*4]) = make_uint2(lo, hi);
            }
        }
        // barrier 2: K, V^T (cross-wave operands) visible
        __syncthreads();

        // ===== S^T = MFMA(K, Q) -> D[krow][qrow]; lane: qrow=l15, 4 consec krows =====
        v8s qf = *reinterpret_cast<const v8s*>(&sm[qrow_base + quad*8]);   // own-wave
        v4f S[W];
#pragma unroll
        for (int ct = 0; ct < W; ++ct) {
            v8s kf = *reinterpret_cast<const v8s*>(&sm[o_k + (ct*16+l15)*QP + quad*8]);
            S[ct] = MFMA(kf, qf, vzero);
        }
        // ===== softmax over keys (per-lane row; tree reduce then xor 16,32) =====
        float cm[W];
#pragma unroll
        for (int ct = 0; ct < W; ++ct)
            cm[ct] = fmaxf(fmaxf(S[ct][0], S[ct][1]), fmaxf(S[ct][2], S[ct][3]));
        float mm = cm[0];
#pragma unroll
        for (int ct = 1; ct < W; ++ct) mm = fmaxf(mm, cm[ct]);
        mm = fmaxf(mm, __shfl_xor(mm, 16));
        mm = fmaxf(mm, __shfl_xor(mm, 32));
        float ss = 0.f;
#pragma unroll
        for (int ct = 0; ct < W; ++ct)
#pragma unroll
            for (int r = 0; r < 4; ++r) { float p = __expf(S[ct][r] - mm); S[ct][r] = p; ss += p; }
        ss += __shfl_xor(ss, 16);
        ss += __shfl_xor(ss, 32);
        float rl = 1.f / ss;       // deferred: applied to O, not to P (softmax linear in P)

        // ===== O^T = MFMA(V^T, P) via quarter P staging buffer (wave-local) =====
        // P packed directly from S per-ks (no pkv array -> no extra VGPR liveness)
        v4f Oacc[2] = { vzero, vzero };
#pragma unroll
        for (int ks = 0; ks < NR/32; ++ks) {
            u32 a0 = pk2(S[2*ks  ][0], S[2*ks  ][1]);
            u32 a1 = pk2(S[2*ks  ][2], S[2*ks  ][3]);
            u32 a2 = pk2(S[2*ks+1][0], S[2*ks+1][1]);
            u32 a3 = pk2(S[2*ks+1][2], S[2*ks+1][3]);
            *reinterpret_cast<uint2*>(&sm[prow_base +      quad*4]) = make_uint2(a0, a1);
            *reinterpret_cast<uint2*>(&sm[prow_base + 16 + quad*4]) = make_uint2(a2, a3);
            v8s pf = *reinterpret_cast<const v8s*>(&sm[prow_base + quad*8]);  // own-wave, in-order DS
#pragma unroll
            for (int nt = 0; nt < 2; ++nt) {
                v8s vf = *reinterpret_cast<const v8s*>(&sm[o_vt + (nt*16+l15)*NRp + ks*32 + quad*8]);
                Oacc[nt] = MFMA(vf, pf, Oacc[nt]);
            }
        }
        // O into Q container (own-wave row; qf already consumed), rl folded here
#pragma unroll
        for (int nt = 0; nt < 2; ++nt) {
            u32 lo = pk2(Oacc[nt][0]*rl, Oacc[nt][1]*rl);
            u32 hi = pk2(Oacc[nt][2]*rl, Oacc[nt][3]*rl);
            *reinterpret_cast<uint2*>(&sm[qrow_base + nt*16 + quad*4]) = make_uint2(lo, hi);
        }

        // ===== out^T += MFMA(Wo^T, O) -> D[d][qrow]; lane = 4 consec d =====
        v8s of = *reinterpret_cast<const v8s*>(&sm[qrow_base + quad*8]);   // own-wave
        {
            const u16* wb = wol + h*2048;
#pragma unroll
            for (int nt = 0; nt < 4; ++nt) {
                v8s wf = *reinterpret_cast<const v8s*>(wb + (nt*16+l15)*32 + quad*8);
                outAcc[nt] = MFMA(wf, of, outAcc[nt]);
            }
        }
    }

    // ===== epilogue: lane owns row w*16+l15, d = nt*16+quad*4 .. +3 (float4) =====
    float* orow = out + base + (w*16 + l15)*rstride;
#pragma unroll
    for (int nt = 0; nt < 4; ++nt) {
        int d0 = nt*16 + quad*4;
        float4 b4 = *reinterpret_cast<const float4*>(bo + d0);
        float4 v = make_float4(outAcc[nt][0]+b4.x, outAcc[nt][1]+b4.y,
                               outAcc[nt][2]+b4.z, outAcc[nt][3]+b4.w);
        if (MODE == 1) {
            float4 p = *reinterpret_cast<const float4*>(orow + d0);
            v.x += p.x; v.y += p.y; v.z += p.z; v.w += p.w;
        }
        *reinterpret_cast<float4*>(orow + d0) = v;
    }
}

extern "C" void kernel_launch(void* const* d_in, const int* in_sizes, int n_in,
                              void* d_out, int out_size, void* d_ws, size_t ws_size,
                              hipStream_t stream) {
    const float* x   = (const float*)d_in[0];
    const float* tqw = (const float*)d_in[1];  const float* tqb = (const float*)d_in[2];
    const float* tkw = (const float*)d_in[3];  const float* tkb = (const float*)d_in[4];
    const float* tvw = (const float*)d_in[5];  const float* tvb = (const float*)d_in[6];
    const float* fqw = (const float*)d_in[7];  const float* fqb = (const float*)d_in[8];
    const float* fkw = (const float*)d_in[9];  const float* fkb = (const float*)d_in[10];
    const float* fvw = (const float*)d_in[11]; const float* fvb = (const float*)d_in[12];
    const float* tow = (const float*)d_in[13]; const float* tob = (const float*)d_in[14];
    const float* fow = (const float*)d_in[15]; const float* fob = (const float*)d_in[16];
    float* out = (float*)d_out;
    u16* ws = (u16*)d_ws;   // 128 KB

    hipLaunchKernelGGL(prep_weights, dim3(256), dim3(256), 0, stream,
                       tqw, tkw, tvw, fqw, fkw, fvw, tow, fow, ws);
    hipLaunchKernelGGL((axial_mfma<64,0>), dim3(Bb*Ff), dim3(256), 0, stream,
                       x, ws, tqb, tkb, tvb, tob, out);
    hipLaunchKernelGGL((axial_mfma<128,1>), dim3(Bb*Tt), dim3(512), 0, stream,
                       x, ws, fqb, fkb, fvb, fob, out);
}

// Round 4
// 384.423 us; speedup vs baseline: 1.1471x; 1.0255x over previous
//
#include <hip/hip_runtime.h>

typedef unsigned short u16;
typedef unsigned int   u32;
typedef short v8s __attribute__((ext_vector_type(8)));   // 8 bf16 (A/B frag, 4 VGPR)
typedef float v4f __attribute__((ext_vector_type(4)));   // 4 fp32 (C/D frag)
typedef u32   v4u __attribute__((ext_vector_type(4)));

#define DEV __device__ __forceinline__
#define MFMA(a,b,c) __builtin_amdgcn_mfma_f32_16x16x32_bf16((a),(b),(c),0,0,0)

constexpr int Bb = 32, Tt = 64, Ff = 128, Dd = 64, Hh = 4, Kk = 32;

DEV u16 f2b(float f) {                       // RNE (prep kernel only)
    u32 u = __float_as_uint(f);
    return (u16)((u + 0x7fffu + ((u >> 16) & 1u)) >> 16);
}
// HW packed f32->bf16 (RNE), 1 VALU op for 2 values (learn_hip T12 recipe)
DEV u32 pk2(float a, float b) {
    u32 r;
    asm("v_cvt_pk_bf16_f32 %0, %1, %2" : "=v"(r) : "v"(a), "v"(b));
    return r;
}

// D-layout -> B-frag redistribution, fully in-register (replaces LDS round-trip).
// Source: two 16-row D tiles (t0,t1); lane (qs,l15) holds lo_t=pk2(row qs*4,+1),
// hi_t=pk2(row qs*4+2,+3), col l15.  Target B-frag: lane (q,l15) needs rows
// q*8..q*8+7 of the 32-row container, col l15:
//   rows q*8..+3  = tile(q>>1), src quad 2*(q&1)   -> its (lo,hi)
//   rows q*8+4..7 = tile(q>>1), src quad 2*(q&1)+1 -> its (lo,hi)
// i.e. sA=((q&1)<<5)|l15, sB=sA+16, tile select by q>>1.  8 bpermute + 4 sel.
DEV v8s redist(u32 lo0, u32 hi0, u32 lo1, u32 hi1, int sA, int sB, int hiHalf) {
    int aL0 = __shfl((int)lo0, sA), aH0 = __shfl((int)hi0, sA);
    int aL1 = __shfl((int)lo1, sA), aH1 = __shfl((int)hi1, sA);
    int bL0 = __shfl((int)lo0, sB), bH0 = __shfl((int)hi0, sB);
    int bL1 = __shfl((int)lo1, sB), bH1 = __shfl((int)hi1, sB);
    v4u r;
    r[0] = (u32)(hiHalf ? aL1 : aL0);
    r[1] = (u32)(hiHalf ? aH1 : aH0);
    r[2] = (u32)(hiHalf ? bL1 : bL0);
    r[3] = (u32)(hiHalf ? bH1 : bH0);
    union { v4u u; v8s s; } c; c.u = r;
    return c.s;
}

// ---- prep: convert all weights to bf16 containers in ws (128 KB) ----
// ws layout (u16):
//   [0, 49152)      : 6 proj  x [h][ch=32][d=64]   (tq,tk,tv,fq,fk,fv)
//   [49152, 65536)  : 2 woT   x [h][d=64][k=32]    (to, fo)
__global__ __launch_bounds__(256)
void prep_weights(const float* __restrict__ tq, const float* __restrict__ tk,
                  const float* __restrict__ tv, const float* __restrict__ fq,
                  const float* __restrict__ fk, const float* __restrict__ fv,
                  const float* __restrict__ to_, const float* __restrict__ fo,
                  u16* __restrict__ ws)
{
    int idx = blockIdx.x * 256 + threadIdx.x;          // 0..65535
    if (idx < 49152) {
        int p = idx >> 13, rem = idx & 8191;           // [h][ch][d]
        int h = rem >> 11, ch = (rem >> 6) & 31, d = rem & 63;
        const float* w = (p==0)?tq:(p==1)?tk:(p==2)?tv:(p==3)?fq:(p==4)?fk:fv;
        ws[idx] = f2b(w[d*128 + h*32 + ch]);           // w[d][h][ch]
    } else {
        int i2 = idx - 49152;
        int path = i2 >> 13, rem = i2 & 8191;          // [h][d][k]
        int h = rem >> 11, d = (rem >> 5) & 63, k2 = rem & 31;
        const float* w = path ? fo : to_;
        ws[idx] = f2b(w[h*2048 + k2*64 + d]);          // wo[h][k][d]
    }
}

// Fragment facts (HW-verified, learn_hip m89/m120):
//   A-frag: lane = A[m][k], m=lane&15, k=quad*8+j  (container row-major [m][k])
//   B-frag: lane = B[k][n], n=lane&15, k=quad*8+j  (container [n][k])
//   C/D:    lane = D[row][col], col=lane&15, row=quad*4+r
//   MFMA(A,B) -> D[m][n] = sum_k A[m][k]*B[n][k]; swapping operands transposes D.
// MODE 0: temporal (NR=64 rows=T, block per (b,f)), writes fp32 partial.
// MODE 1: feature (NR=128 rows=F, block per (b,t)), read-add-write final.
//
// Structure: Q, P, O never touch LDS — each was written and read back by the
// SAME wave purely to perform the D-layout -> B-frag permutation, which
// redist() now does in-register (8 bpermute + 4 cndmask each).  Only K and V^T
// (cross-wave operands) live in LDS, double-buffered per head so a single
// barrier per head suffices (write buf[h&1]; barrier; read buf[h&1]; h+2's
// writes can't pass h+1's barrier, and each wave's reads drain before it
// arrives at a barrier).  LDS: feature 37888 B, temporal 19456 B.
// No min-waves launch_bounds: round 1 showed forcing 8 waves/EU (64-reg cap)
// causes catastrophic scratch spills (WRITE 315 MB vs 66 MB ideal).
template<int NR, int MODE>
__global__ __launch_bounds__(NR*4)
void axial_mfma(const float* __restrict__ x, const u16* __restrict__ wsw,
                const float* __restrict__ bq, const float* __restrict__ bk,
                const float* __restrict__ bv, const float* __restrict__ bo,
                float* __restrict__ out)
{
    constexpr int W   = NR / 16;      // waves per block
    constexpr int QP  = 40;           // K row pitch (80B: 16B-aligned)
    constexpr int NRp = NR + 8;       // V^T pitch (16B-aligned)
    constexpr int BUF = NR * QP + 32 * NRp;   // one K+V^T buffer (u16)
    constexpr int SMEM = 2 * BUF;             // feature: 37888 B, temporal: 19456 B
    __shared__ alignas(16) u16 sm[SMEM];

    const int tid  = threadIdx.x;
    const int w    = tid >> 6;
    const int lane = tid & 63;
    const int quad = lane >> 4;
    const int l15  = lane & 15;
    const int bid  = blockIdx.x;

    // redist lane geometry (uniform per thread)
    const int sA = ((quad & 1) << 5) | l15;
    const int sB = sA + 16;
    const int hiH = quad >> 1;

    int base, rstride;
    if (MODE == 0) { int b = bid >> 7, f = bid & 127; base = b*(Tt*Ff*Dd) + f*Dd; rstride = Ff*Dd; }
    else           { base = bid * (Ff*Dd); rstride = Dd; }

    constexpr int PB = (MODE == 0) ? 0 : 3;
    const u16* wql = wsw + (PB+0)*8192;
    const u16* wkl = wsw + (PB+1)*8192;
    const u16* wvl = wsw + (PB+2)*8192;
    const u16* wol = wsw + 49152 + MODE*8192;

    // ---- X fragments (dual-use as A or B; same lane mapping), row w*16+l15 ----
    v8s xfrag[2];
#pragma unroll
    for (int ks = 0; ks < 2; ++ks) {
        const float* xp = x + base + (w*16 + l15)*rstride + ks*32 + quad*8;
        float4 a = *reinterpret_cast<const float4*>(xp);
        float4 b = *reinterpret_cast<const float4*>(xp + 4);
        v8s f;
        u32* fu = reinterpret_cast<u32*>(&f);
        fu[0] = pk2(a.x, a.y); fu[1] = pk2(a.z, a.w);
        fu[2] = pk2(b.x, b.y); fu[3] = pk2(b.z, b.w);
        xfrag[ks] = f;
    }

    v4f outAcc[4];
#pragma unroll
    for (int i = 0; i < 4; ++i) outAcc[i] = (v4f){0.f,0.f,0.f,0.f};

    const float scale = 0.17677669529663687f;   // 1/sqrt(32)
    const v4f vzero = (v4f){0.f,0.f,0.f,0.f};

#pragma unroll 1
    for (int h = 0; h < Hh; ++h) {
        const int bb   = (h & 1) * BUF;     // double-buffer select
        const int o_k  = bb;
        const int o_vt = bb + NR * QP;

        // ===== Q^T proj: MFMA(Wq^T, X) -> D[ch][qrow]; stays in registers =====
        u32 qlo[2], qhi[2];
        {
            const u16* wb = wql + h*2048;
#pragma unroll
            for (int nt = 0; nt < 2; ++nt) {
                v4f acc = vzero;
#pragma unroll
                for (int ks = 0; ks < 2; ++ks) {
                    v8s wf = *reinterpret_cast<const v8s*>(wb + (nt*16+l15)*64 + ks*32 + quad*8);
                    acc = MFMA(wf, xfrag[ks], acc);
                }
                float4 b4 = *reinterpret_cast<const float4*>(bq + h*32 + nt*16 + quad*4);
                qlo[nt] = pk2((acc[0]+b4.x)*scale, (acc[1]+b4.y)*scale);
                qhi[nt] = pk2((acc[2]+b4.z)*scale, (acc[3]+b4.w)*scale);
            }
        }
        v8s qf = redist(qlo[0], qhi[0], qlo[1], qhi[1], sA, sB, hiH);

        // ===== K^T proj -> LDS [krow][ch] (cross-wave operand) =====
        {
            const u16* wb = wkl + h*2048;
#pragma unroll
            for (int nt = 0; nt < 2; ++nt) {
                v4f acc = vzero;
#pragma unroll
                for (int ks = 0; ks < 2; ++ks) {
                    v8s wf = *reinterpret_cast<const v8s*>(wb + (nt*16+l15)*64 + ks*32 + quad*8);
                    acc = MFMA(wf, xfrag[ks], acc);
                }
                float4 b4 = *reinterpret_cast<const float4*>(bk + h*32 + nt*16 + quad*4);
                u32 lo = pk2(acc[0]+b4.x, acc[1]+b4.y);
                u32 hi = pk2(acc[2]+b4.z, acc[3]+b4.w);
                *reinterpret_cast<uint2*>(&sm[o_k + (w*16+l15)*QP + nt*16 + quad*4]) = make_uint2(lo, hi);
            }
        }
        // ===== V proj -> LDS V^T [ch][krow] (cross-wave operand) =====
        {
            const u16* wb = wvl + h*2048;
#pragma unroll
            for (int nt = 0; nt < 2; ++nt) {
                v4f acc = vzero;
#pragma unroll
                for (int ks = 0; ks < 2; ++ks) {
                    v8s wf = *reinterpret_cast<const v8s*>(wb + (nt*16+l15)*64 + ks*32 + quad*8);
                    acc = MFMA(xfrag[ks], wf, acc);
                }
                float bias = bv[h*32 + nt*16 + l15];
                u32 lo = pk2(acc[0]+bias, acc[1]+bias);
                u32 hi = pk2(acc[2]+bias, acc[3]+bias);
                int ch = nt*16 + l15;
                *reinterpret_cast<uint2*>(&sm[o_vt + ch*NRp + w*16 + quad*4]) = make_uint2(lo, hi);
            }
        }
        // single barrier per head: K/V^T of THIS buffer visible to all waves
        __syncthreads();

        // ===== S^T = MFMA(K, Q) -> D[krow][qrow]; lane: qrow=l15, 4 consec krows =====
        v4f S[W];
#pragma unroll
        for (int ct = 0; ct < W; ++ct) {
            v8s kf = *reinterpret_cast<const v8s*>(&sm[o_k + (ct*16+l15)*QP + quad*8]);
            S[ct] = MFMA(kf, qf, vzero);
        }
        // ===== softmax over keys (per-lane row; tree reduce then xor 16,32) =====
        float cm[W];
#pragma unroll
        for (int ct = 0; ct < W; ++ct)
            cm[ct] = fmaxf(fmaxf(S[ct][0], S[ct][1]), fmaxf(S[ct][2], S[ct][3]));
        float mm = cm[0];
#pragma unroll
        for (int ct = 1; ct < W; ++ct) mm = fmaxf(mm, cm[ct]);
        mm = fmaxf(mm, __shfl_xor(mm, 16));
        mm = fmaxf(mm, __shfl_xor(mm, 32));
        float ss = 0.f;
        u32 pl[2*W];                     // packed unnormalized P per tile (lo,hi)
#pragma unroll
        for (int ct = 0; ct < W; ++ct) {
            float p0 = __expf(S[ct][0] - mm), p1 = __expf(S[ct][1] - mm);
            float p2 = __expf(S[ct][2] - mm), p3 = __expf(S[ct][3] - mm);
            ss += (p0 + p1) + (p2 + p3);
            pl[2*ct  ] = pk2(p0, p1);
            pl[2*ct+1] = pk2(p2, p3);
        }
        ss += __shfl_xor(ss, 16);
        ss += __shfl_xor(ss, 32);
        float rl = 1.f / ss;       // deferred: applied to O (softmax linear in P)

        // ===== O^T = MFMA(V^T, P); P redistributed in-register per ks =====
        v4f Oacc[2] = { vzero, vzero };
#pragma unroll
        for (int ks = 0; ks < NR/32; ++ks) {
            v8s pf = redist(pl[4*ks], pl[4*ks+1], pl[4*ks+2], pl[4*ks+3], sA, sB, hiH);
#pragma unroll
            for (int nt = 0; nt < 2; ++nt) {
                v8s vf = *reinterpret_cast<const v8s*>(&sm[o_vt + (nt*16+l15)*NRp + ks*32 + quad*8]);
                Oacc[nt] = MFMA(vf, pf, Oacc[nt]);
            }
        }
        // O normalized + packed + redistributed in-register
        u32 olo[2], ohi[2];
#pragma unroll
        for (int nt = 0; nt < 2; ++nt) {
            olo[nt] = pk2(Oacc[nt][0]*rl, Oacc[nt][1]*rl);
            ohi[nt] = pk2(Oacc[nt][2]*rl, Oacc[nt][3]*rl);
        }
        v8s of = redist(olo[0], ohi[0], olo[1], ohi[1], sA, sB, hiH);

        // ===== out^T += MFMA(Wo^T, O) -> D[d][qrow]; lane = 4 consec d =====
        {
            const u16* wb = wol + h*2048;
#pragma unroll
            for (int nt = 0; nt < 4; ++nt) {
                v8s wf = *reinterpret_cast<const v8s*>(wb + (nt*16+l15)*32 + quad*8);
                outAcc[nt] = MFMA(wf, of, outAcc[nt]);
            }
        }
    }

    // ===== epilogue: lane owns row w*16+l15, d = nt*16+quad*4 .. +3 (float4) =====
    float* orow = out + base + (w*16 + l15)*rstride;
#pragma unroll
    for (int nt = 0; nt < 4; ++nt) {
        int d0 = nt*16 + quad*4;
        float4 b4 = *reinterpret_cast<const float4*>(bo + d0);
        float4 v = make_float4(outAcc[nt][0]+b4.x, outAcc[nt][1]+b4.y,
                               outAcc[nt][2]+b4.z, outAcc[nt][3]+b4.w);
        if (MODE == 1) {
            float4 p = *reinterpret_cast<const float4*>(orow + d0);
            v.x += p.x; v.y += p.y; v.z += p.z; v.w += p.w;
        }
        *reinterpret_cast<float4*>(orow + d0) = v;
    }
}

extern "C" void kernel_launch(void* const* d_in, const int* in_sizes, int n_in,
                              void* d_out, int out_size, void* d_ws, size_t ws_size,
                              hipStream_t stream) {
    const float* x   = (const float*)d_in[0];
    const float* tqw = (const float*)d_in[1];  const float* tqb = (const float*)d_in[2];
    const float* tkw = (const float*)d_in[3];  const float* tkb = (const float*)d_in[4];
    const float* tvw = (const float*)d_in[5];  const float* tvb = (const float*)d_in[6];
    const float* fqw = (const float*)d_in[7];  const float* fqb = (const float*)d_in[8];
    const float* fkw = (const float*)d_in[9];  const float* fkb = (const float*)d_in[10];
    const float* fvw = (const float*)d_in[11]; const float* fvb = (const float*)d_in[12];
    const float* tow = (const float*)d_in[13]; const float* tob = (const float*)d_in[14];
    const float* fow = (const float*)d_in[15]; const float* fob = (const float*)d_in[16];
    float* out = (float*)d_out;
    u16* ws = (u16*)d_ws;   // 128 KB

    hipLaunchKernelGGL(prep_weights, dim3(256), dim3(256), 0, stream,
                       tqw, tkw, tvw, fqw, fkw, fvw, tow, fow, ws);
    hipLaunchKernelGGL((axial_mfma<64,0>), dim3(Bb*Ff), dim3(256), 0, stream,
                       x, ws, tqb, tkb, tvb, tob, out);
    hipLaunchKernelGGL((axial_mfma<128,1>), dim3(Bb*Tt), dim3(512), 0, stream,
                       x, ws, fqb, fkb, fvb, fob, out);
}

// Round 8
// 352.743 us; speedup vs baseline: 1.2501x; 1.0898x over previous
//
#include <hip/hip_runtime.h>

typedef unsigned short u16;
typedef unsigned int   u32;
typedef short v8s __attribute__((ext_vector_type(8)));   // 8 bf16 (A/B frag, 4 VGPR)
typedef float v4f __attribute__((ext_vector_type(4)));   // 4 fp32 (C/D frag)
typedef u32   v4u __attribute__((ext_vector_type(4)));

#define DEV __device__ __forceinline__
#define MFMA(a,b,c) __builtin_amdgcn_mfma_f32_16x16x32_bf16((a),(b),(c),0,0,0)

constexpr int Bb = 32, Tt = 64, Ff = 128, Dd = 64, Hh = 4, Kk = 32;

DEV u16 f2b(float f) {                       // RNE (prep kernel only)
    u32 u = __float_as_uint(f);
    return (u16)((u + 0x7fffu + ((u >> 16) & 1u)) >> 16);
}
// HW packed f32->bf16 (RNE), 1 VALU op for 2 values (learn_hip T12 recipe)
DEV u32 pk2(float a, float b) {
    u32 r;
    asm("v_cvt_pk_bf16_f32 %0, %1, %2" : "=v"(r) : "v"(a), "v"(b));
    return r;
}

// D-layout -> frag redistribution, fully in-register (harness-verified round 4).
// Generic semantics: given a 32xN container stored as two 16-row D-tiles
// (t0 = rows 0-15, t1 = rows 16-31; D-tile lane (qs,l15) holds lo=pk2(row
// qs*4,+1), hi=pk2(row qs*4+2,+3) at col l15), produce the frag where lane
// (q,l15) holds container rows q*8..q*8+7 at col l15 — which is BOTH the
// B-frag (n=l15, k=quad*8+j) and the A-frag (m=l15, k=quad*8+j) layout.
//   sA=((q&1)<<5)|l15, sB=sA+16, tile select hiHalf=q>>1.
DEV v8s redist(u32 lo0, u32 hi0, u32 lo1, u32 hi1, int sA, int sB, int hiHalf) {
    int aL0 = __shfl((int)lo0, sA), aH0 = __shfl((int)hi0, sA);
    int aL1 = __shfl((int)lo1, sA), aH1 = __shfl((int)hi1, sA);
    int bL0 = __shfl((int)lo0, sB), bH0 = __shfl((int)hi0, sB);
    int bL1 = __shfl((int)lo1, sB), bH1 = __shfl((int)hi1, sB);
    v4u r;
    r[0] = (u32)(hiHalf ? aL1 : aL0);
    r[1] = (u32)(hiHalf ? aH1 : aH0);
    r[2] = (u32)(hiHalf ? bL1 : bL0);
    r[3] = (u32)(hiHalf ? bH1 : bH0);
    union { v4u u; v8s s; } c; c.u = r;
    return c.s;
}

// ---- prep: convert all weights to bf16 containers in ws (128 KB) ----
// (byte-identical to round 4 — NO scale folding)
// ws layout (u16):
//   [0, 49152)      : 6 proj  x [h][ch=32][d=64]   (tq,tk,tv,fq,fk,fv)
//   [49152, 65536)  : 2 woT   x [h][d=64][k=32]    (to, fo)
__global__ __launch_bounds__(256)
void prep_weights(const float* __restrict__ tq, const float* __restrict__ tk,
                  const float* __restrict__ tv, const float* __restrict__ fq,
                  const float* __restrict__ fk, const float* __restrict__ fv,
                  const float* __restrict__ to_, const float* __restrict__ fo,
                  u16* __restrict__ ws)
{
    int idx = blockIdx.x * 256 + threadIdx.x;          // 0..65535
    if (idx < 49152) {
        int p = idx >> 13, rem = idx & 8191;           // [h][ch][d]
        int h = rem >> 11, ch = (rem >> 6) & 31, d = rem & 63;
        const float* w = (p==0)?tq:(p==1)?tk:(p==2)?tv:(p==3)?fq:(p==4)?fk:fv;
        ws[idx] = f2b(w[d*128 + h*32 + ch]);           // w[d][h][ch]
    } else {
        int i2 = idx - 49152;
        int path = i2 >> 13, rem = i2 & 8191;          // [h][d][k]
        int h = rem >> 11, d = (rem >> 5) & 63, k2 = rem & 31;
        const float* w = path ? fo : to_;
        ws[idx] = f2b(w[h*2048 + k2*64 + d]);          // wo[h][k][d]
    }
}

// ===================== TEMPORAL: one wave per (rh, b, f) =====================
// Zero LDS, zero barriers.  The wave owns 32 q-rows (rh half) of the 64-row
// temporal attention for one (b,f) column, and computes ALL 64 rows' K and V
// itself (2x proj redundancy; rh-pair shares X via same-XCD L2 because
// bid = rh*4096 + bf keeps bid%8 equal for the pair).  Every operand
// (K,V,Q,P,O) lives in registers via redist() — no cross-wave communication
// exists, so no race/barrier hazard class at all (rounds 5/6 lesson).
// Rule #20 (learn_hip r286): NO runtime-indexed ext_vector arrays — the
// wave's own q-tiles are hoisted into xq_[][] via branchless rh-select with
// static indices.
// Fragment facts (HW-verified, learn_hip m89/m120 + round-4 harness pass):
//   A-frag: lane = A[m][k], m=lane&15, k=quad*8+j
//   B-frag: lane = B[k][n], n=lane&15, k=quad*8+j
//   C/D:    lane = D[row][col], col=lane&15, row=quad*4+r
__global__ __launch_bounds__(64)
void temporal_wave(const float* __restrict__ x, const u16* __restrict__ wsw,
                   const float* __restrict__ bq, const float* __restrict__ bk,
                   const float* __restrict__ bv, const float* __restrict__ bo,
                   float* __restrict__ out)
{
    const int lane = threadIdx.x;          // 64-thread block = 1 wave
    const int quad = lane >> 4;
    const int l15  = lane & 15;
    const int bid  = blockIdx.x;
    const int rh   = bid >> 12;            // 0/1: which 32-row half this wave outputs
    const int bf   = bid & 4095;
    const int b    = bf >> 7, f = bf & 127;
    const int base = b*(Tt*Ff*Dd) + f*Dd;
    constexpr int rstride = Ff*Dd;

    const int sA = ((quad & 1) << 5) | l15;
    const int sB = sA + 16;
    const int hiH = quad >> 1;

    const u16* wql = wsw + 0*8192;         // temporal weight bank
    const u16* wkl = wsw + 1*8192;
    const u16* wvl = wsw + 2*8192;
    const u16* wol = wsw + 49152;          // to

    // ---- X frags for ALL 64 rows (needed as A for V-proj, B for K/Q-proj) ----
    v8s xf[4][2];                          // [kt: 16-row tile][ks: 32-d half]
#pragma unroll
    for (int kt = 0; kt < 4; ++kt)
#pragma unroll
        for (int ks = 0; ks < 2; ++ks) {
            const float* xp = x + base + (kt*16 + l15)*rstride + ks*32 + quad*8;
            float4 a = *reinterpret_cast<const float4*>(xp);
            float4 c = *reinterpret_cast<const float4*>(xp + 4);
            v8s fr;
            u32* fu = reinterpret_cast<u32*>(&fr);
            fu[0] = pk2(a.x, a.y); fu[1] = pk2(a.z, a.w);
            fu[2] = pk2(c.x, c.y); fu[3] = pk2(c.z, c.w);
            xf[kt][ks] = fr;
        }

    // this wave's own q-tiles, selected ONCE with static indices (rule #20)
    v8s xq_[2][2];
#pragma unroll
    for (int qt = 0; qt < 2; ++qt)
#pragma unroll
        for (int ks = 0; ks < 2; ++ks)
            xq_[qt][ks] = rh ? xf[2+qt][ks] : xf[qt][ks];

    v4f outAcc[2][4];                      // [qt][nt] fp32 out accumulator
#pragma unroll
    for (int i = 0; i < 2; ++i)
#pragma unroll
        for (int j = 0; j < 4; ++j) outAcc[i][j] = (v4f){0.f,0.f,0.f,0.f};

    const float scale = 0.17677669529663687f;   // 1/sqrt(32)
    const v4f vzero = (v4f){0.f,0.f,0.f,0.f};

#pragma unroll 1
    for (int h = 0; h < Hh; ++h) {
        // ===== K proj: D[ch][krow] per (kt,nt); redist(nt0,nt1) -> A-frag =====
        // kf[kt]: lane = K[krow=l15 (in tile kt)][ch=quad*8+j]
        v8s kf[4];
#pragma unroll
        for (int kt = 0; kt < 4; ++kt) {
            u32 lo[2], hi[2];
#pragma unroll
            for (int nt = 0; nt < 2; ++nt) {
                v4f acc = vzero;
#pragma unroll
                for (int ks = 0; ks < 2; ++ks) {
                    v8s wf = *reinterpret_cast<const v8s*>(wkl + h*2048 + (nt*16+l15)*64 + ks*32 + quad*8);
                    acc = MFMA(wf, xf[kt][ks], acc);
                }
                float4 b4 = *reinterpret_cast<const float4*>(bk + h*32 + nt*16 + quad*4);
                lo[nt] = pk2(acc[0]+b4.x, acc[1]+b4.y);
                hi[nt] = pk2(acc[2]+b4.z, acc[3]+b4.w);
            }
            kf[kt] = redist(lo[0], hi[0], lo[1], hi[1], sA, sB, hiH);
        }

        // ===== V proj: D[krow][ch] per (kt,nt); redist(kt-pair) -> A-frag =====
        // vf[w][nt]: lane = V^T[ch=nt*16+l15][krow=quad*8+j (in 32-window w)]
        u32 vlo[4][2], vhi[4][2];
#pragma unroll
        for (int kt = 0; kt < 4; ++kt)
#pragma unroll
            for (int nt = 0; nt < 2; ++nt) {
                v4f acc = vzero;
#pragma unroll
                for (int ks = 0; ks < 2; ++ks) {
                    v8s wf = *reinterpret_cast<const v8s*>(wvl + h*2048 + (nt*16+l15)*64 + ks*32 + quad*8);
                    acc = MFMA(xf[kt][ks], wf, acc);
                }
                float bias = bv[h*32 + nt*16 + l15];
                vlo[kt][nt] = pk2(acc[0]+bias, acc[1]+bias);
                vhi[kt][nt] = pk2(acc[2]+bias, acc[3]+bias);
            }
        v8s vf[2][2];
#pragma unroll
        for (int w2 = 0; w2 < 2; ++w2)
#pragma unroll
            for (int nt = 0; nt < 2; ++nt)
                vf[w2][nt] = redist(vlo[2*w2][nt], vhi[2*w2][nt],
                                    vlo[2*w2+1][nt], vhi[2*w2+1][nt], sA, sB, hiH);

        // ===== per q-tile (2 tiles = this wave's 32 rows): Q, S, softmax, PV, out =====
#pragma unroll
        for (int qt = 0; qt < 2; ++qt) {
            // Q^T proj -> D[ch][qrow]; redist -> B-frag
            u32 qlo[2], qhi[2];
#pragma unroll
            for (int nt = 0; nt < 2; ++nt) {
                v4f acc = vzero;
#pragma unroll
                for (int ks = 0; ks < 2; ++ks) {
                    v8s wf = *reinterpret_cast<const v8s*>(wql + h*2048 + (nt*16+l15)*64 + ks*32 + quad*8);
                    acc = MFMA(wf, xq_[qt][ks], acc);
                }
                float4 b4 = *reinterpret_cast<const float4*>(bq + h*32 + nt*16 + quad*4);
                qlo[nt] = pk2((acc[0]+b4.x)*scale, (acc[1]+b4.y)*scale);
                qhi[nt] = pk2((acc[2]+b4.z)*scale, (acc[3]+b4.w)*scale);
            }
            v8s qf = redist(qlo[0], qhi[0], qlo[1], qhi[1], sA, sB, hiH);

            // S^T = MFMA(K, Q) -> D[krow][qrow]; lane: qrow=l15, 4 consec krows
            v4f S[4];
#pragma unroll
            for (int kt = 0; kt < 4; ++kt)
                S[kt] = MFMA(kf[kt], qf, vzero);

            // softmax over 64 keys (per-lane 16 vals; xor 16,32 joins quads)
            float cm[4];
#pragma unroll
            for (int kt = 0; kt < 4; ++kt)
                cm[kt] = fmaxf(fmaxf(S[kt][0], S[kt][1]), fmaxf(S[kt][2], S[kt][3]));
            float mm = fmaxf(fmaxf(cm[0], cm[1]), fmaxf(cm[2], cm[3]));
            mm = fmaxf(mm, __shfl_xor(mm, 16));
            mm = fmaxf(mm, __shfl_xor(mm, 32));
            float ss = 0.f;
            u32 pl[8];
#pragma unroll
            for (int kt = 0; kt < 4; ++kt) {
                float p0 = __expf(S[kt][0] - mm), p1 = __expf(S[kt][1] - mm);
                float p2 = __expf(S[kt][2] - mm), p3 = __expf(S[kt][3] - mm);
                ss += (p0 + p1) + (p2 + p3);
                pl[2*kt  ] = pk2(p0, p1);
                pl[2*kt+1] = pk2(p2, p3);
            }
            ss += __shfl_xor(ss, 16);
            ss += __shfl_xor(ss, 32);
            float rl = 1.f / ss;           // deferred to O pack (softmax linear in P)

            // O^T = MFMA(V^T, P) over 2 krow-windows
            v4f Oacc[2] = { vzero, vzero };
#pragma unroll
            for (int w2 = 0; w2 < 2; ++w2) {
                v8s pf = redist(pl[4*w2], pl[4*w2+1], pl[4*w2+2], pl[4*w2+3], sA, sB, hiH);
#pragma unroll
                for (int nt = 0; nt < 2; ++nt)
                    Oacc[nt] = MFMA(vf[w2][nt], pf, Oacc[nt]);
            }
            u32 olo[2], ohi[2];
#pragma unroll
            for (int nt = 0; nt < 2; ++nt) {
                olo[nt] = pk2(Oacc[nt][0]*rl, Oacc[nt][1]*rl);
                ohi[nt] = pk2(Oacc[nt][2]*rl, Oacc[nt][3]*rl);
            }
            v8s of = redist(olo[0], ohi[0], olo[1], ohi[1], sA, sB, hiH);

            // out^T += MFMA(Wo^T, O) -> D[d][qrow]
#pragma unroll
            for (int nt = 0; nt < 4; ++nt) {
                v8s wf = *reinterpret_cast<const v8s*>(wol + h*2048 + (nt*16+l15)*32 + quad*8);
                outAcc[qt][nt] = MFMA(wf, of, outAcc[qt][nt]);
            }
        }
    }

    // ===== epilogue: row = rh*32 + qt*16 + l15; plain fp32 write (runs first) =====
#pragma unroll
    for (int qt = 0; qt < 2; ++qt) {
        float* orow = out + base + (rh*32 + qt*16 + l15)*rstride;
#pragma unroll
        for (int nt = 0; nt < 4; ++nt) {
            int d0 = nt*16 + quad*4;
            float4 b4 = *reinterpret_cast<const float4*>(bo + d0);
            float4 v = make_float4(outAcc[qt][nt][0]+b4.x, outAcc[qt][nt][1]+b4.y,
                                   outAcc[qt][nt][2]+b4.z, outAcc[qt][nt][3]+b4.w);
            *reinterpret_cast<float4*>(orow + d0) = v;
        }
    }
}

// ============ FEATURE: byte-identical to round 4 (harness-verified) ============
// MODE 1: feature (NR=128 rows=F, block per (b,t)), read-add-write final.
template<int NR, int MODE>
__global__ __launch_bounds__(NR*4)
void axial_mfma(const float* __restrict__ x, const u16* __restrict__ wsw,
                const float* __restrict__ bq, const float* __restrict__ bk,
                const float* __restrict__ bv, const float* __restrict__ bo,
                float* __restrict__ out)
{
    constexpr int W   = NR / 16;      // waves per block
    constexpr int QP  = 40;           // K row pitch (80B: 16B-aligned)
    constexpr int NRp = NR + 8;       // V^T pitch (16B-aligned)
    constexpr int BUF = NR * QP + 32 * NRp;   // one K+V^T buffer (u16)
    constexpr int SMEM = 2 * BUF;             // feature: 37888 B
    __shared__ alignas(16) u16 sm[SMEM];

    const int tid  = threadIdx.x;
    const int w    = tid >> 6;
    const int lane = tid & 63;
    const int quad = lane >> 4;
    const int l15  = lane & 15;
    const int bid  = blockIdx.x;

    const int sA = ((quad & 1) << 5) | l15;
    const int sB = sA + 16;
    const int hiH = quad >> 1;

    int base, rstride;
    if (MODE == 0) { int b = bid >> 7, f = bid & 127; base = b*(Tt*Ff*Dd) + f*Dd; rstride = Ff*Dd; }
    else           { base = bid * (Ff*Dd); rstride = Dd; }

    constexpr int PB = (MODE == 0) ? 0 : 3;
    const u16* wql = wsw + (PB+0)*8192;
    const u16* wkl = wsw + (PB+1)*8192;
    const u16* wvl = wsw + (PB+2)*8192;
    const u16* wol = wsw + 49152 + MODE*8192;

    v8s xfrag[2];
#pragma unroll
    for (int ks = 0; ks < 2; ++ks) {
        const float* xp = x + base + (w*16 + l15)*rstride + ks*32 + quad*8;
        float4 a = *reinterpret_cast<const float4*>(xp);
        float4 b = *reinterpret_cast<const float4*>(xp + 4);
        v8s f;
        u32* fu = reinterpret_cast<u32*>(&f);
        fu[0] = pk2(a.x, a.y); fu[1] = pk2(a.z, a.w);
        fu[2] = pk2(b.x, b.y); fu[3] = pk2(b.z, b.w);
        xfrag[ks] = f;
    }

    v4f outAcc[4];
#pragma unroll
    for (int i = 0; i < 4; ++i) outAcc[i] = (v4f){0.f,0.f,0.f,0.f};

    const float scale = 0.17677669529663687f;   // 1/sqrt(32)
    const v4f vzero = (v4f){0.f,0.f,0.f,0.f};

#pragma unroll 1
    for (int h = 0; h < Hh; ++h) {
        const int bb   = (h & 1) * BUF;     // double-buffer select
        const int o_k  = bb;
        const int o_vt = bb + NR * QP;

        // ===== Q^T proj: MFMA(Wq^T, X) -> D[ch][qrow]; stays in registers =====
        u32 qlo[2], qhi[2];
        {
            const u16* wb = wql + h*2048;
#pragma unroll
            for (int nt = 0; nt < 2; ++nt) {
                v4f acc = vzero;
#pragma unroll
                for (int ks = 0; ks < 2; ++ks) {
                    v8s wf = *reinterpret_cast<const v8s*>(wb + (nt*16+l15)*64 + ks*32 + quad*8);
                    acc = MFMA(wf, xfrag[ks], acc);
                }
                float4 b4 = *reinterpret_cast<const float4*>(bq + h*32 + nt*16 + quad*4);
                qlo[nt] = pk2((acc[0]+b4.x)*scale, (acc[1]+b4.y)*scale);
                qhi[nt] = pk2((acc[2]+b4.z)*scale, (acc[3]+b4.w)*scale);
            }
        }
        v8s qf = redist(qlo[0], qhi[0], qlo[1], qhi[1], sA, sB, hiH);

        // ===== K^T proj -> LDS [krow][ch] (cross-wave operand) =====
        {
            const u16* wb = wkl + h*2048;
#pragma unroll
            for (int nt = 0; nt < 2; ++nt) {
                v4f acc = vzero;
#pragma unroll
                for (int ks = 0; ks < 2; ++ks) {
                    v8s wf = *reinterpret_cast<const v8s*>(wb + (nt*16+l15)*64 + ks*32 + quad*8);
                    acc = MFMA(wf, xfrag[ks], acc);
                }
                float4 b4 = *reinterpret_cast<const float4*>(bk + h*32 + nt*16 + quad*4);
                u32 lo = pk2(acc[0]+b4.x, acc[1]+b4.y);
                u32 hi = pk2(acc[2]+b4.z, acc[3]+b4.w);
                *reinterpret_cast<uint2*>(&sm[o_k + (w*16+l15)*QP + nt*16 + quad*4]) = make_uint2(lo, hi);
            }
        }
        // ===== V proj -> LDS V^T [ch][krow] (cross-wave operand) =====
        {
            const u16* wb = wvl + h*2048;
#pragma unroll
            for (int nt = 0; nt < 2; ++nt) {
                v4f acc = vzero;
#pragma unroll
                for (int ks = 0; ks < 2; ++ks) {
                    v8s wf = *reinterpret_cast<const v8s*>(wb + (nt*16+l15)*64 + ks*32 + quad*8);
                    acc = MFMA(xfrag[ks], wf, acc);
                }
                float bias = bv[h*32 + nt*16 + l15];
                u32 lo = pk2(acc[0]+bias, acc[1]+bias);
                u32 hi = pk2(acc[2]+bias, acc[3]+bias);
                int ch = nt*16 + l15;
                *reinterpret_cast<uint2*>(&sm[o_vt + ch*NRp + w*16 + quad*4]) = make_uint2(lo, hi);
            }
        }
        // single barrier per head: K/V^T of THIS buffer visible to all waves
        __syncthreads();

        // ===== S^T = MFMA(K, Q) -> D[krow][qrow]; lane: qrow=l15, 4 consec krows =====
        v4f S[W];
#pragma unroll
        for (int ct = 0; ct < W; ++ct) {
            v8s kf = *reinterpret_cast<const v8s*>(&sm[o_k + (ct*16+l15)*QP + quad*8]);
            S[ct] = MFMA(kf, qf, vzero);
        }
        // ===== softmax over keys (per-lane row; tree reduce then xor 16,32) =====
        float cm[W];
#pragma unroll
        for (int ct = 0; ct < W; ++ct)
            cm[ct] = fmaxf(fmaxf(S[ct][0], S[ct][1]), fmaxf(S[ct][2], S[ct][3]));
        float mm = cm[0];
#pragma unroll
        for (int ct = 1; ct < W; ++ct) mm = fmaxf(mm, cm[ct]);
        mm = fmaxf(mm, __shfl_xor(mm, 16));
        mm = fmaxf(mm, __shfl_xor(mm, 32));
        float ss = 0.f;
        u32 pl[2*W];                     // packed unnormalized P per tile (lo,hi)
#pragma unroll
        for (int ct = 0; ct < W; ++ct) {
            float p0 = __expf(S[ct][0] - mm), p1 = __expf(S[ct][1] - mm);
            float p2 = __expf(S[ct][2] - mm), p3 = __expf(S[ct][3] - mm);
            ss += (p0 + p1) + (p2 + p3);
            pl[2*ct  ] = pk2(p0, p1);
            pl[2*ct+1] = pk2(p2, p3);
        }
        ss += __shfl_xor(ss, 16);
        ss += __shfl_xor(ss, 32);
        float rl = 1.f / ss;       // deferred: applied to O (softmax linear in P)

        // ===== O^T = MFMA(V^T, P); P redistributed in-register per ks =====
        v4f Oacc[2] = { vzero, vzero };
#pragma unroll
        for (int ks = 0; ks < NR/32; ++ks) {
            v8s pf = redist(pl[4*ks], pl[4*ks+1], pl[4*ks+2], pl[4*ks+3], sA, sB, hiH);
#pragma unroll
            for (int nt = 0; nt < 2; ++nt) {
                v8s vf = *reinterpret_cast<const v8s*>(&sm[o_vt + (nt*16+l15)*NRp + ks*32 + quad*8]);
                Oacc[nt] = MFMA(vf, pf, Oacc[nt]);
            }
        }
        // O normalized + packed + redistributed in-register
        u32 olo[2], ohi[2];
#pragma unroll
        for (int nt = 0; nt < 2; ++nt) {
            olo[nt] = pk2(Oacc[nt][0]*rl, Oacc[nt][1]*rl);
            ohi[nt] = pk2(Oacc[nt][2]*rl, Oacc[nt][3]*rl);
        }
        v8s of = redist(olo[0], ohi[0], olo[1], ohi[1], sA, sB, hiH);

        // ===== out^T += MFMA(Wo^T, O) -> D[d][qrow]; lane = 4 consec d =====
        {
            const u16* wb = wol + h*2048;
#pragma unroll
            for (int nt = 0; nt < 4; ++nt) {
                v8s wf = *reinterpret_cast<const v8s*>(wb + (nt*16+l15)*32 + quad*8);
                outAcc[nt] = MFMA(wf, of, outAcc[nt]);
            }
        }
    }

    // ===== epilogue: lane owns row w*16+l15, d = nt*16+quad*4 .. +3 (float4) =====
    float* orow = out + base + (w*16 + l15)*rstride;
#pragma unroll
    for (int nt = 0; nt < 4; ++nt) {
        int d0 = nt*16 + quad*4;
        float4 b4 = *reinterpret_cast<const float4*>(bo + d0);
        float4 v = make_float4(outAcc[nt][0]+b4.x, outAcc[nt][1]+b4.y,
                               outAcc[nt][2]+b4.z, outAcc[nt][3]+b4.w);
        if (MODE == 1) {
            float4 p = *reinterpret_cast<const float4*>(orow + d0);
            v.x += p.x; v.y += p.y; v.z += p.z; v.w += p.w;
        }
        *reinterpret_cast<float4*>(orow + d0) = v;
    }
}

extern "C" void kernel_launch(void* const* d_in, const int* in_sizes, int n_in,
                              void* d_out, int out_size, void* d_ws, size_t ws_size,
                              hipStream_t stream) {
    const float* x   = (const float*)d_in[0];
    const float* tqw = (const float*)d_in[1];  const float* tqb = (const float*)d_in[2];
    const float* tkw = (const float*)d_in[3];  const float* tkb = (const float*)d_in[4];
    const float* tvw = (const float*)d_in[5];  const float* tvb = (const float*)d_in[6];
    const float* fqw = (const float*)d_in[7];  const float* fqb = (const float*)d_in[8];
    const float* fkw = (const float*)d_in[9];  const float* fkb = (const float*)d_in[10];
    const float* fvw = (const float*)d_in[11]; const float* fvb = (const float*)d_in[12];
    const float* tow = (const float*)d_in[13]; const float* tob = (const float*)d_in[14];
    const float* fow = (const float*)d_in[15]; const float* fob = (const float*)d_in[16];
    float* out = (float*)d_out;
    u16* ws = (u16*)d_ws;   // 128 KB

    hipLaunchKernelGGL(prep_weights, dim3(256), dim3(256), 0, stream,
                       tqw, tkw, tvw, fqw, fkw, fvw, tow, fow, ws);
    hipLaunchKernelGGL(temporal_wave, dim3(2*Bb*Ff), dim3(64), 0, stream,
                       x, ws, tqb, tkb, tvb, tob, out);
    hipLaunchKernelGGL((axial_mfma<128,1>), dim3(Bb*Tt), dim3(512), 0, stream,
                       x, ws, fqb, fkb, fvb, fob, out);
}